// Round 10
// baseline (444.195 us; speedup 1.0000x reference)
//
#include <hip/hip_runtime.h>

#define NN 100000
#define NE 1600000
#define NBK 782   // ceil(NN/128) 128-node buckets
#define NBLK 256  // persistent blocks for counting sort
#define CHUNK ((NE + NBLK - 1) / NBLK)  // 6250

typedef __bf16 bf16x2 __attribute__((ext_vector_type(2)));
typedef __bf16 bf16x4 __attribute__((ext_vector_type(4)));
typedef __bf16 bf16x8 __attribute__((ext_vector_type(8)));
typedef float f32x4 __attribute__((ext_vector_type(4)));

// ---------------- privatized counting sort by dst-bucket ----------------
// Edge record packed: (src << 7) | (dst & 127). Zero contended global atomics.

__global__ __launch_bounds__(256) void k1_hist(const int* __restrict__ dst, int* __restrict__ bhist) {
  __shared__ int h[NBK];
  int tid = threadIdx.x, b = blockIdx.x;
  for (int i = tid; i < NBK; i += 256) h[i] = 0;
  __syncthreads();
  int base = b * CHUNK, end = min(base + CHUNK, NE);
  for (int e = base + tid; e < end; e += 256) atomicAdd(&h[dst[e] >> 7], 1);
  __syncthreads();
  for (int i = tid; i < NBK; i += 256) bhist[b * NBK + i] = h[i];  // [block][bin]
}

// Fused column-reduce + scan + per-(block,bin) base. Replaces kA/kB/kC.
// All bhist accesses are ROW-wise (coalesced) — old kA/kC column reads had 16x
// fetch amplification. blockbase layout: [block][bin] so k3 reads its row.
__global__ __launch_bounds__(1024) void kABC(const int* __restrict__ bhist, int* __restrict__ bptr,
                                             int* __restrict__ blockbase) {
  __shared__ int s[1024];
  int j = threadIdx.x;  // bin
  int tot = 0;
  if (j < NBK) {
#pragma unroll 8
    for (int t = 0; t < NBLK; ++t) tot += bhist[t * NBK + j];
  }
  s[j] = (j < NBK) ? tot : 0;
  __syncthreads();
  for (int off = 1; off < 1024; off <<= 1) {
    int t = (j >= off) ? s[j - off] : 0;
    __syncthreads();
    s[j] += t;
    __syncthreads();
  }
  int run = 0;
  if (j < NBK) {
    bptr[j + 1] = s[j];
    run = s[j] - tot;  // exclusive bin base
    if (j == 0) bptr[0] = 0;
#pragma unroll 8
    for (int t = 0; t < NBLK; ++t) {
      blockbase[t * NBK + j] = run;  // coalesced write
      run += bhist[t * NBK + j];     // coalesced read
    }
  }
}

__global__ __launch_bounds__(256) void k3_scatter(const int* __restrict__ src, const int* __restrict__ dst,
                                                  const int* __restrict__ blockbase, int* __restrict__ bucketed) {
  __shared__ int cur[NBK];
  int tid = threadIdx.x, b = blockIdx.x;
  for (int i = tid; i < NBK; i += 256) cur[i] = blockbase[b * NBK + i];  // row-wise, coalesced
  __syncthreads();
  int base = b * CHUNK, end = min(base + CHUNK, NE);
  for (int e = base + tid; e < end; e += 256) {
    int d = dst[e];
    int pos = atomicAdd(&cur[d >> 7], 1);
    bucketed[pos] = (src[e] << 7) | (d & 127);
  }
}

// Fused: per-bucket degree histogram + dis + in-bucket scan -> row_ptr directly.
// row_ptr[node+1] = bptr[bucket] + inclusive_scan(deg within bucket).
// Replaces k_deg + 3 global-scan kernels.
__global__ __launch_bounds__(256) void k_deg2(const int* __restrict__ bucketed, const int* __restrict__ bptr,
                                              int* __restrict__ row_ptr, float* __restrict__ dis) {
  __shared__ int deg[128];
  __shared__ int sc[128];
  int b = blockIdx.x, tid = threadIdx.x;
  int nb0 = b << 7;
  if (tid < 128) deg[tid] = 0;
  __syncthreads();
  int beg = bptr[b], end = bptr[b + 1];
  for (int e = beg + tid; e < end; e += 256) atomicAdd(&deg[bucketed[e] & 127], 1);
  __syncthreads();
  if (tid < 128) sc[tid] = deg[tid];
  __syncthreads();
  for (int off = 1; off < 128; off <<= 1) {
    int t = (tid >= off && tid < 128) ? sc[tid - off] : 0;
    __syncthreads();
    if (tid < 128) sc[tid] += t;
    __syncthreads();
  }
  if (tid < 128 && nb0 + tid < NN) {
    row_ptr[nb0 + tid + 1] = beg + sc[tid];
    dis[nb0 + tid] = rsqrtf((float)(deg[tid] + 1));
    if (b == 0 && tid == 0) row_ptr[0] = 0;
  }
}

__global__ __launch_bounds__(256) void k_csrfill(const int* __restrict__ bucketed, const int* __restrict__ bptr,
                                                 const int* __restrict__ row_ptr, int* __restrict__ csr_src) {
  __shared__ int cur[128];
  int b = blockIdx.x, tid = threadIdx.x;
  int nb0 = b << 7;
  if (tid < 128 && nb0 + tid < NN) cur[tid] = row_ptr[nb0 + tid];
  __syncthreads();
  int beg = bptr[b], end = bptr[b + 1];
  for (int e = beg + tid; e < end; e += 256) {
    int pk = bucketed[e];
    int pos = atomicAdd(&cur[pk & 127], 1);
    csr_src[pos] = pk >> 7;
  }
}

// ---------------- bf16 MFMA GEMM: tmp[m,n] = dis[m] * (xform(A[m,:]) @ W)[n] ----------------

template <int BN, int MODE>
__global__ __launch_bounds__(256) void k_gemm(const void* __restrict__ Av, const float* __restrict__ W,
                                              const float* __restrict__ bias, const float* __restrict__ dis,
                                              __bf16* __restrict__ out) {
  constexpr int LDK = 72;
  constexpr int NSH = (BN == 128) ? 7 : 6;
  constexpr int NT = BN / 32;
  __shared__ __bf16 lA[128 * LDK];
  __shared__ __bf16 lB[BN * LDK];

  const int tid = threadIdx.x;
  const int rowBase = blockIdx.x * 128;
  const int lane = tid & 63;
  const int wid = tid >> 6;
  const int wm = (wid & 1) * 64;
  const int wn = (wid >> 1) * (BN / 2);
  const int lm = lane & 15;
  const int kg = lane >> 4;

  f32x4 acc[4][NT] = {};

  for (int kb = 0; kb < 128; kb += 64) {
    if constexpr (MODE == 0) {
      const float* A = (const float*)Av;
      for (int i = tid; i < 128 * 16; i += 256) {
        int r = i >> 4;
        int c4 = (i & 15) * 4;
        int gr = rowBase + r;
        float4 v = make_float4(0.f, 0.f, 0.f, 0.f);
        if (gr < NN) v = *(const float4*)(A + (size_t)gr * 128 + kb + c4);
        bf16x4 bv = {(__bf16)v.x, (__bf16)v.y, (__bf16)v.z, (__bf16)v.w};
        *(bf16x4*)&lA[r * LDK + c4] = bv;
      }
    } else {
      const __bf16* A = (const __bf16*)Av;
      for (int i = tid; i < 128 * 8; i += 256) {
        int r = i >> 3;
        int c8 = (i & 7) * 8;
        int gr = rowBase + r;
        int gk = kb + c8;
        bf16x8 v = {};
        if (gr < NN) v = *(const bf16x8*)(A + (size_t)gr * 128 + gk);
        bf16x8 o;
#pragma unroll
        for (int j = 0; j < 8; ++j) o[j] = (__bf16)fmaxf((float)v[j] + bias[gk + j], 0.f);
        *(bf16x8*)&lA[r * LDK + c8] = o;
      }
    }
    for (int i = tid; i < 64 * BN; i += 256) {
      int n = i & (BN - 1);
      int k = i >> NSH;
      lB[n * LDK + k] = (__bf16)W[(size_t)(kb + k) * BN + n];
    }
    __syncthreads();
#pragma unroll
    for (int kk = 0; kk < 64; kk += 32) {
      bf16x8 af[4], bfr[NT];
#pragma unroll
      for (int tm = 0; tm < 4; ++tm)
        af[tm] = *(const bf16x8*)&lA[(wm + tm * 16 + lm) * LDK + kk + kg * 8];
#pragma unroll
      for (int tn = 0; tn < NT; ++tn)
        bfr[tn] = *(const bf16x8*)&lB[(wn + tn * 16 + lm) * LDK + kk + kg * 8];
#pragma unroll
      for (int tm = 0; tm < 4; ++tm)
#pragma unroll
        for (int tn = 0; tn < NT; ++tn)
          acc[tm][tn] = __builtin_amdgcn_mfma_f32_16x16x32_bf16(af[tm], bfr[tn], acc[tm][tn], 0, 0, 0);
    }
    __syncthreads();
  }

#pragma unroll
  for (int tm = 0; tm < 4; ++tm) {
    int r0 = rowBase + wm + tm * 16 + kg * 4;
#pragma unroll
    for (int tn = 0; tn < NT; ++tn) {
      int c0 = wn + tn * 16 + lm;
#pragma unroll
      for (int r = 0; r < 4; ++r) {
        int gr = r0 + r;
        if (gr < NN) out[(size_t)gr * BN + c0] = (__bf16)(acc[tm][tn][r] * dis[gr]);
      }
    }
  }
}

// ---------------- grouped pull aggregation (F=128): at LLC compulsory floor ----------------

__global__ __launch_bounds__(256) void k_agg128(const __bf16* __restrict__ tmp, const int* __restrict__ row_ptr,
                                                const int* __restrict__ csr_src, const float* __restrict__ dis,
                                                __bf16* __restrict__ agg) {
  int wid = (blockIdx.x * 256 + threadIdx.x) >> 6;
  int lane = threadIdx.x & 63;
  if (wid >= NN) return;
  int grp = lane >> 4;   // 0..3
  int fl = lane & 15;    // features [fl*8, fl*8+8)

  float acc[8];
  if (grp == 0) {
    bf16x8 sv = *(const bf16x8*)&tmp[(size_t)wid * 128 + fl * 8];
#pragma unroll
    for (int t = 0; t < 8; ++t) acc[t] = (float)sv[t];
  } else {
#pragma unroll
    for (int t = 0; t < 8; ++t) acc[t] = 0.f;
  }

  int beg = row_ptr[wid];
  int end = row_ptr[wid + 1];
  for (int base = beg; base < end; base += 64) {
    int cnt = min(64, end - base);
    int sidx = (base + lane < end) ? csr_src[base + lane] : 0;
    int i = 0;
    for (; i + 16 <= cnt; i += 16) {
      bf16x8 v[4];
#pragma unroll
      for (int u = 0; u < 4; ++u) {
        int s = __shfl(sidx, i + u * 4 + grp);
        v[u] = *(const bf16x8*)&tmp[(size_t)s * 128 + fl * 8];
      }
#pragma unroll
      for (int u = 0; u < 4; ++u)
#pragma unroll
        for (int t = 0; t < 8; ++t) acc[t] += (float)v[u][t];
    }
    for (; i + 4 <= cnt; i += 4) {
      int s = __shfl(sidx, i + grp);
      bf16x8 v = *(const bf16x8*)&tmp[(size_t)s * 128 + fl * 8];
#pragma unroll
      for (int t = 0; t < 8; ++t) acc[t] += (float)v[t];
    }
    if (i < cnt) {
      int idx = i + grp;
      int s = __shfl(sidx, idx & 63);
      if (idx < cnt) {
        bf16x8 v = *(const bf16x8*)&tmp[(size_t)s * 128 + fl * 8];
#pragma unroll
        for (int t = 0; t < 8; ++t) acc[t] += (float)v[t];
      }
    }
  }

#pragma unroll
  for (int t = 0; t < 8; ++t) acc[t] += __shfl_xor(acc[t], 16);
#pragma unroll
  for (int t = 0; t < 8; ++t) acc[t] += __shfl_xor(acc[t], 32);

  if (grp == 0) {
    float d = dis[wid];
    bf16x8 o;
#pragma unroll
    for (int t = 0; t < 8; ++t) o[t] = (__bf16)(acc[t] * d);
    *(bf16x8*)&agg[(size_t)wid * 128 + fl * 8] = o;
  }
}

// ---------------- F=64 grouped aggregation fused with bias+relu+log_softmax ----------------
// 8 groups x 8 lanes; each group gathers a different edge's 128 B row with
// 16 B/lane loads -> 8 edges (2 KB) per load inst, unroll-2 = 16 edges in flight.

__global__ __launch_bounds__(256) void k_agg64_final(const __bf16* __restrict__ tmp, const int* __restrict__ row_ptr,
                                                     const int* __restrict__ csr_src, const float* __restrict__ dis,
                                                     const float* __restrict__ b2, float* __restrict__ out) {
  int wid = (blockIdx.x * 256 + threadIdx.x) >> 6;
  int lane = threadIdx.x & 63;
  if (wid >= NN) return;
  int grp = lane >> 3;  // 0..7
  int fl = lane & 7;    // features [fl*8, fl*8+8)

  float acc[8];
  if (grp == 0) {
    bf16x8 sv = *(const bf16x8*)&tmp[(size_t)wid * 64 + fl * 8];
#pragma unroll
    for (int t = 0; t < 8; ++t) acc[t] = (float)sv[t];
  } else {
#pragma unroll
    for (int t = 0; t < 8; ++t) acc[t] = 0.f;
  }

  int beg = row_ptr[wid];
  int end = row_ptr[wid + 1];
  for (int base = beg; base < end; base += 64) {
    int cnt = min(64, end - base);
    int sidx = (base + lane < end) ? csr_src[base + lane] : 0;
    int i = 0;
    for (; i + 16 <= cnt; i += 16) {
      int s0 = __shfl(sidx, i + grp);
      int s1 = __shfl(sidx, i + 8 + grp);
      bf16x8 v0 = *(const bf16x8*)&tmp[(size_t)s0 * 64 + fl * 8];
      bf16x8 v1 = *(const bf16x8*)&tmp[(size_t)s1 * 64 + fl * 8];
#pragma unroll
      for (int t = 0; t < 8; ++t) acc[t] += (float)v0[t] + (float)v1[t];
    }
    for (; i + 8 <= cnt; i += 8) {
      int s = __shfl(sidx, i + grp);
      bf16x8 v = *(const bf16x8*)&tmp[(size_t)s * 64 + fl * 8];
#pragma unroll
      for (int t = 0; t < 8; ++t) acc[t] += (float)v[t];
    }
    if (i < cnt) {
      int idx = i + grp;
      int s = __shfl(sidx, idx & 63);
      if (idx < cnt) {
        bf16x8 v = *(const bf16x8*)&tmp[(size_t)s * 64 + fl * 8];
#pragma unroll
        for (int t = 0; t < 8; ++t) acc[t] += (float)v[t];
      }
    }
  }

  // combine 8 group partials (xor over lane bits 3,4,5) -> every lane holds full sums
#pragma unroll
  for (int t = 0; t < 8; ++t) acc[t] += __shfl_xor(acc[t], 8);
#pragma unroll
  for (int t = 0; t < 8; ++t) acc[t] += __shfl_xor(acc[t], 16);
#pragma unroll
  for (int t = 0; t < 8; ++t) acc[t] += __shfl_xor(acc[t], 32);

  // fused epilogue: relu(acc*dis + b2) -> log_softmax. Lanes with equal fl are
  // bitwise-identical duplicates (x8), so wave-sum of exp = 8 * true sum.
  float d = dis[wid];
  float v[8], lm_ = -1e30f;
#pragma unroll
  for (int t = 0; t < 8; ++t) {
    v[t] = fmaxf(acc[t] * d + b2[fl * 8 + t], 0.f);
    lm_ = fmaxf(lm_, v[t]);
  }
#pragma unroll
  for (int off = 32; off > 0; off >>= 1) lm_ = fmaxf(lm_, __shfl_xor(lm_, off));
  float le = 0.f;
#pragma unroll
  for (int t = 0; t < 8; ++t) le += expf(v[t] - lm_);
#pragma unroll
  for (int off = 32; off > 0; off >>= 1) le += __shfl_xor(le, off);
  float logss = logf(le * 0.125f);
  if (grp == 0) {
    float4 o0 = make_float4(v[0] - lm_ - logss, v[1] - lm_ - logss, v[2] - lm_ - logss, v[3] - lm_ - logss);
    float4 o1 = make_float4(v[4] - lm_ - logss, v[5] - lm_ - logss, v[6] - lm_ - logss, v[7] - lm_ - logss);
    *(float4*)&out[(size_t)wid * 64 + fl * 8] = o0;
    *(float4*)&out[(size_t)wid * 64 + fl * 8 + 4] = o1;
  }
}

// ---------------- launch ----------------

extern "C" void kernel_launch(void* const* d_in, const int* in_sizes, int n_in,
                              void* d_out, int out_size, void* d_ws, size_t ws_size,
                              hipStream_t stream) {
  const float* x  = (const float*)d_in[0];
  const int*   ei = (const int*)d_in[1];
  const float* W0 = (const float*)d_in[2];
  const float* b0 = (const float*)d_in[3];
  const float* W1 = (const float*)d_in[4];
  const float* b1 = (const float*)d_in[5];
  const float* W2 = (const float*)d_in[6];
  const float* b2 = (const float*)d_in[7];
  const int* esrc = ei;
  const int* edst = ei + NE;

  char* p = (char*)d_ws;
  auto alloc = [&](size_t bytes) {
    char* q = p;
    p += (bytes + 255) & ~(size_t)255;
    return q;
  };
  float*  dis     = (float*)alloc((size_t)NN * 4);
  int*    row_ptr = (int*)alloc((size_t)(NN + 1) * 4);
  int*    bptr    = (int*)alloc((NBK + 1) * 4);
  int*    csr_src = (int*)alloc((size_t)NE * 4);            // 6.4 MB
  __bf16* tmp     = (__bf16*)alloc((size_t)NN * 128 * 2);   // 25.6 MB
  int*    bucketed  = (int*)tmp;                            // 6.4 MB alias (packed edges)
  int*    bhist     = csr_src;                              // 800 KB alias
  int*    blockbase = csr_src + NBLK * NBK;                 // 800 KB alias

  k1_hist<<<NBLK, 256, 0, stream>>>(edst, bhist);
  kABC<<<1, 1024, 0, stream>>>(bhist, bptr, blockbase);
  k3_scatter<<<NBLK, 256, 0, stream>>>(esrc, edst, blockbase, bucketed);
  k_deg2<<<NBK, 256, 0, stream>>>(bucketed, bptr, row_ptr, dis);
  k_csrfill<<<NBK, 256, 0, stream>>>(bucketed, bptr, row_ptr, csr_src);

  int gblocks = (NN + 127) / 128;
  int ablocks = (NN * 64 + 255) / 256;

  k_gemm<128, 0><<<gblocks, 256, 0, stream>>>(x, W0, nullptr, dis, tmp);
  k_agg128<<<ablocks, 256, 0, stream>>>(tmp, row_ptr, csr_src, dis, (__bf16*)d_out);

  k_gemm<128, 2><<<gblocks, 256, 0, stream>>>(d_out, W1, b0, dis, tmp);
  k_agg128<<<ablocks, 256, 0, stream>>>(tmp, row_ptr, csr_src, dis, (__bf16*)d_out);

  k_gemm<64, 2><<<gblocks, 256, 0, stream>>>(d_out, W2, b1, dis, tmp);
  k_agg64_final<<<ablocks, 256, 0, stream>>>(tmp, row_ptr, csr_src, dis, b2, (float*)d_out);
}

// Round 11
// 439.924 us; speedup vs baseline: 1.0097x; 1.0097x over previous
//
#include <hip/hip_runtime.h>

#define NN 100000
#define NE 1600000
#define NBK 782   // ceil(NN/128) 128-node buckets
#define NBLK 256  // persistent blocks for counting sort
#define CHUNK ((NE + NBLK - 1) / NBLK)  // 6250

typedef __bf16 bf16x2 __attribute__((ext_vector_type(2)));
typedef __bf16 bf16x4 __attribute__((ext_vector_type(4)));
typedef __bf16 bf16x8 __attribute__((ext_vector_type(8)));
typedef float f32x4 __attribute__((ext_vector_type(4)));

// ---------------- privatized counting sort by dst-bucket ----------------
// bhist layout: [bin][block] (transposed vs r10) so per-bin rows are contiguous.
// Edge record packed: (src << 7) | (dst & 127).

__global__ __launch_bounds__(256) void k1_hist(const int* __restrict__ dst, int* __restrict__ bhist) {
  __shared__ int h[NBK];
  int tid = threadIdx.x, b = blockIdx.x;
  for (int i = tid; i < NBK; i += 256) h[i] = 0;
  __syncthreads();
  int base = b * CHUNK, end = min(base + CHUNK, NE);
  for (int e = base + tid; e < end; e += 256) atomicAdd(&h[dst[e] >> 7], 1);
  __syncthreads();
  for (int i = tid; i < NBK; i += 256) bhist[i * NBLK + b] = h[i];  // [bin][block]
}

// one wave per bin: coalesced int4 row-reduce -> btot[bin]
__global__ __launch_bounds__(256) void kA2(const int* __restrict__ bhist, int* __restrict__ btot) {
  int w = threadIdx.x >> 6, lane = threadIdx.x & 63;
  int bin = blockIdx.x * 4 + w;
  if (bin >= NBK) return;
  int4 v = *(const int4*)(bhist + bin * NBLK + lane * 4);
  int s = v.x + v.y + v.z + v.w;
#pragma unroll
  for (int off = 32; off > 0; off >>= 1) s += __shfl_xor(s, off);
  if (lane == 0) btot[bin] = s;
}

__global__ __launch_bounds__(1024) void kB_bscan(const int* __restrict__ btot, int* __restrict__ bptr) {
  __shared__ int s[1024];
  int tid = threadIdx.x;
  int v = (tid < NBK) ? btot[tid] : 0;
  s[tid] = v;
  __syncthreads();
  for (int off = 1; off < 1024; off <<= 1) {
    int t = (tid >= off) ? s[tid - off] : 0;
    __syncthreads();
    s[tid] += t;
    __syncthreads();
  }
  if (tid < NBK) bptr[tid + 1] = s[tid];
  if (tid == 0) bptr[0] = 0;
}

// one wave per bin: wave-scan over 256 per-block counts -> blockbase[bin][block]
__global__ __launch_bounds__(256) void kC2(const int* __restrict__ bhist, const int* __restrict__ bptr,
                                           int* __restrict__ blockbase) {
  int w = threadIdx.x >> 6, lane = threadIdx.x & 63;
  int bin = blockIdx.x * 4 + w;
  if (bin >= NBK) return;
  int4 v = *(const int4*)(bhist + bin * NBLK + lane * 4);
  int ls = v.x + v.y + v.z + v.w;
  int incl = ls;
#pragma unroll
  for (int off = 1; off < 64; off <<= 1) {
    int t = __shfl_up(incl, off);
    if (lane >= off) incl += t;
  }
  int base = bptr[bin] + incl - ls;  // exclusive across lanes
  int4 o;
  o.x = base;
  o.y = base + v.x;
  o.z = base + v.x + v.y;
  o.w = base + v.x + v.y + v.z;
  *(int4*)(blockbase + bin * NBLK + lane * 4) = o;
}

__global__ __launch_bounds__(256) void k3_scatter(const int* __restrict__ src, const int* __restrict__ dst,
                                                  const int* __restrict__ blockbase, int* __restrict__ bucketed) {
  __shared__ int cur[NBK];
  int tid = threadIdx.x, b = blockIdx.x;
  for (int i = tid; i < NBK; i += 256) cur[i] = blockbase[i * NBLK + b];
  __syncthreads();
  int base = b * CHUNK, end = min(base + CHUNK, NE);
  for (int e = base + tid; e < end; e += 256) {
    int d = dst[e];
    int pos = atomicAdd(&cur[d >> 7], 1);
    bucketed[pos] = (src[e] << 7) | (d & 127);
  }
}

// Fused per-bucket: degree histogram -> dis + row_ptr + cursors -> csr fill.
// Second sweep over the bucket's 8 KB edge slice is an L2 hit.
__global__ __launch_bounds__(256) void k_degfill(const int* __restrict__ bucketed, const int* __restrict__ bptr,
                                                 int* __restrict__ row_ptr, float* __restrict__ dis,
                                                 int* __restrict__ csr_src) {
  __shared__ int deg[128];
  __shared__ int sc[128];
  __shared__ int cur[128];
  int b = blockIdx.x, tid = threadIdx.x;
  int nb0 = b << 7;
  if (tid < 128) deg[tid] = 0;
  __syncthreads();
  int beg = bptr[b], end = bptr[b + 1];
  for (int e = beg + tid; e < end; e += 256) atomicAdd(&deg[bucketed[e] & 127], 1);
  __syncthreads();
  if (tid < 128) sc[tid] = deg[tid];
  __syncthreads();
  for (int off = 1; off < 128; off <<= 1) {
    int t = (tid >= off && tid < 128) ? sc[tid - off] : 0;
    __syncthreads();
    if (tid < 128) sc[tid] += t;
    __syncthreads();
  }
  if (tid < 128) {
    cur[tid] = beg + sc[tid] - deg[tid];  // exclusive
    if (nb0 + tid < NN) {
      row_ptr[nb0 + tid + 1] = beg + sc[tid];
      dis[nb0 + tid] = rsqrtf((float)(deg[tid] + 1));
      if (b == 0 && tid == 0) row_ptr[0] = 0;
    }
  }
  __syncthreads();
  for (int e = beg + tid; e < end; e += 256) {
    int pk = bucketed[e];
    int pos = atomicAdd(&cur[pk & 127], 1);
    csr_src[pos] = pk >> 7;
  }
}

// ---------------- bf16 MFMA GEMM: tmp[m,n] = dis[m] * (xform(A[m,:]) @ W)[n] ----------------

template <int BN, int MODE>
__global__ __launch_bounds__(256) void k_gemm(const void* __restrict__ Av, const float* __restrict__ W,
                                              const float* __restrict__ bias, const float* __restrict__ dis,
                                              __bf16* __restrict__ out) {
  constexpr int LDK = 72;
  constexpr int NSH = (BN == 128) ? 7 : 6;
  constexpr int NT = BN / 32;
  __shared__ __bf16 lA[128 * LDK];
  __shared__ __bf16 lB[BN * LDK];

  const int tid = threadIdx.x;
  const int rowBase = blockIdx.x * 128;
  const int lane = tid & 63;
  const int wid = tid >> 6;
  const int wm = (wid & 1) * 64;
  const int wn = (wid >> 1) * (BN / 2);
  const int lm = lane & 15;
  const int kg = lane >> 4;

  f32x4 acc[4][NT] = {};

  for (int kb = 0; kb < 128; kb += 64) {
    if constexpr (MODE == 0) {
      const float* A = (const float*)Av;
      for (int i = tid; i < 128 * 16; i += 256) {
        int r = i >> 4;
        int c4 = (i & 15) * 4;
        int gr = rowBase + r;
        float4 v = make_float4(0.f, 0.f, 0.f, 0.f);
        if (gr < NN) v = *(const float4*)(A + (size_t)gr * 128 + kb + c4);
        bf16x4 bv = {(__bf16)v.x, (__bf16)v.y, (__bf16)v.z, (__bf16)v.w};
        *(bf16x4*)&lA[r * LDK + c4] = bv;
      }
    } else {
      const __bf16* A = (const __bf16*)Av;
      for (int i = tid; i < 128 * 8; i += 256) {
        int r = i >> 3;
        int c8 = (i & 7) * 8;
        int gr = rowBase + r;
        int gk = kb + c8;
        bf16x8 v = {};
        if (gr < NN) v = *(const bf16x8*)(A + (size_t)gr * 128 + gk);
        bf16x8 o;
#pragma unroll
        for (int j = 0; j < 8; ++j) o[j] = (__bf16)fmaxf((float)v[j] + bias[gk + j], 0.f);
        *(bf16x8*)&lA[r * LDK + c8] = o;
      }
    }
    // W staging: float4 coalesced reads, scatter-transpose into LDS
    for (int i = tid; i < 16 * BN; i += 256) {
      int n4 = (i * 4) & (BN - 1);
      int k = (i * 4) >> NSH;
      float4 w = *(const float4*)(W + (size_t)(kb + k) * BN + n4);
      lB[(n4 + 0) * LDK + k] = (__bf16)w.x;
      lB[(n4 + 1) * LDK + k] = (__bf16)w.y;
      lB[(n4 + 2) * LDK + k] = (__bf16)w.z;
      lB[(n4 + 3) * LDK + k] = (__bf16)w.w;
    }
    __syncthreads();
#pragma unroll
    for (int kk = 0; kk < 64; kk += 32) {
      bf16x8 af[4], bfr[NT];
#pragma unroll
      for (int tm = 0; tm < 4; ++tm)
        af[tm] = *(const bf16x8*)&lA[(wm + tm * 16 + lm) * LDK + kk + kg * 8];
#pragma unroll
      for (int tn = 0; tn < NT; ++tn)
        bfr[tn] = *(const bf16x8*)&lB[(wn + tn * 16 + lm) * LDK + kk + kg * 8];
#pragma unroll
      for (int tm = 0; tm < 4; ++tm)
#pragma unroll
        for (int tn = 0; tn < NT; ++tn)
          acc[tm][tn] = __builtin_amdgcn_mfma_f32_16x16x32_bf16(af[tm], bfr[tn], acc[tm][tn], 0, 0, 0);
    }
    __syncthreads();
  }

#pragma unroll
  for (int tm = 0; tm < 4; ++tm) {
    int r0 = rowBase + wm + tm * 16 + kg * 4;
#pragma unroll
    for (int tn = 0; tn < NT; ++tn) {
      int c0 = wn + tn * 16 + lm;
#pragma unroll
      for (int r = 0; r < 4; ++r) {
        int gr = r0 + r;
        if (gr < NN) out[(size_t)gr * BN + c0] = (__bf16)(acc[tm][tn][r] * dis[gr]);
      }
    }
  }
}

// ---------------- grouped pull aggregation (F=128): at LLC compulsory floor ----------------

__global__ __launch_bounds__(256) void k_agg128(const __bf16* __restrict__ tmp, const int* __restrict__ row_ptr,
                                                const int* __restrict__ csr_src, const float* __restrict__ dis,
                                                __bf16* __restrict__ agg) {
  int wid = (blockIdx.x * 256 + threadIdx.x) >> 6;
  int lane = threadIdx.x & 63;
  if (wid >= NN) return;
  int grp = lane >> 4;   // 0..3
  int fl = lane & 15;    // features [fl*8, fl*8+8)

  float acc[8];
  if (grp == 0) {
    bf16x8 sv = *(const bf16x8*)&tmp[(size_t)wid * 128 + fl * 8];
#pragma unroll
    for (int t = 0; t < 8; ++t) acc[t] = (float)sv[t];
  } else {
#pragma unroll
    for (int t = 0; t < 8; ++t) acc[t] = 0.f;
  }

  int beg = row_ptr[wid];
  int end = row_ptr[wid + 1];
  for (int base = beg; base < end; base += 64) {
    int cnt = min(64, end - base);
    int sidx = (base + lane < end) ? csr_src[base + lane] : 0;
    int i = 0;
    for (; i + 16 <= cnt; i += 16) {
      bf16x8 v[4];
#pragma unroll
      for (int u = 0; u < 4; ++u) {
        int s = __shfl(sidx, i + u * 4 + grp);
        v[u] = *(const bf16x8*)&tmp[(size_t)s * 128 + fl * 8];
      }
#pragma unroll
      for (int u = 0; u < 4; ++u)
#pragma unroll
        for (int t = 0; t < 8; ++t) acc[t] += (float)v[u][t];
    }
    for (; i + 4 <= cnt; i += 4) {
      int s = __shfl(sidx, i + grp);
      bf16x8 v = *(const bf16x8*)&tmp[(size_t)s * 128 + fl * 8];
#pragma unroll
      for (int t = 0; t < 8; ++t) acc[t] += (float)v[t];
    }
    if (i < cnt) {
      int idx = i + grp;
      int s = __shfl(sidx, idx & 63);
      if (idx < cnt) {
        bf16x8 v = *(const bf16x8*)&tmp[(size_t)s * 128 + fl * 8];
#pragma unroll
        for (int t = 0; t < 8; ++t) acc[t] += (float)v[t];
      }
    }
  }

#pragma unroll
  for (int t = 0; t < 8; ++t) acc[t] += __shfl_xor(acc[t], 16);
#pragma unroll
  for (int t = 0; t < 8; ++t) acc[t] += __shfl_xor(acc[t], 32);

  if (grp == 0) {
    float d = dis[wid];
    bf16x8 o;
#pragma unroll
    for (int t = 0; t < 8; ++t) o[t] = (__bf16)(acc[t] * d);
    *(bf16x8*)&agg[(size_t)wid * 128 + fl * 8] = o;
  }
}

// ---------------- F=64 grouped aggregation fused with bias+relu+log_softmax ----------------

__global__ __launch_bounds__(256) void k_agg64_final(const __bf16* __restrict__ tmp, const int* __restrict__ row_ptr,
                                                     const int* __restrict__ csr_src, const float* __restrict__ dis,
                                                     const float* __restrict__ b2, float* __restrict__ out) {
  int wid = (blockIdx.x * 256 + threadIdx.x) >> 6;
  int lane = threadIdx.x & 63;
  if (wid >= NN) return;
  int grp = lane >> 3;  // 0..7
  int fl = lane & 7;    // features [fl*8, fl*8+8)

  float acc[8];
  if (grp == 0) {
    bf16x8 sv = *(const bf16x8*)&tmp[(size_t)wid * 64 + fl * 8];
#pragma unroll
    for (int t = 0; t < 8; ++t) acc[t] = (float)sv[t];
  } else {
#pragma unroll
    for (int t = 0; t < 8; ++t) acc[t] = 0.f;
  }

  int beg = row_ptr[wid];
  int end = row_ptr[wid + 1];
  for (int base = beg; base < end; base += 64) {
    int cnt = min(64, end - base);
    int sidx = (base + lane < end) ? csr_src[base + lane] : 0;
    int i = 0;
    for (; i + 16 <= cnt; i += 16) {
      int s0 = __shfl(sidx, i + grp);
      int s1 = __shfl(sidx, i + 8 + grp);
      bf16x8 v0 = *(const bf16x8*)&tmp[(size_t)s0 * 64 + fl * 8];
      bf16x8 v1 = *(const bf16x8*)&tmp[(size_t)s1 * 64 + fl * 8];
#pragma unroll
      for (int t = 0; t < 8; ++t) acc[t] += (float)v0[t] + (float)v1[t];
    }
    for (; i + 8 <= cnt; i += 8) {
      int s = __shfl(sidx, i + grp);
      bf16x8 v = *(const bf16x8*)&tmp[(size_t)s * 64 + fl * 8];
#pragma unroll
      for (int t = 0; t < 8; ++t) acc[t] += (float)v[t];
    }
    if (i < cnt) {
      int idx = i + grp;
      int s = __shfl(sidx, idx & 63);
      if (idx < cnt) {
        bf16x8 v = *(const bf16x8*)&tmp[(size_t)s * 64 + fl * 8];
#pragma unroll
        for (int t = 0; t < 8; ++t) acc[t] += (float)v[t];
      }
    }
  }

#pragma unroll
  for (int t = 0; t < 8; ++t) acc[t] += __shfl_xor(acc[t], 8);
#pragma unroll
  for (int t = 0; t < 8; ++t) acc[t] += __shfl_xor(acc[t], 16);
#pragma unroll
  for (int t = 0; t < 8; ++t) acc[t] += __shfl_xor(acc[t], 32);

  float d = dis[wid];
  float v[8], lm_ = -1e30f;
#pragma unroll
  for (int t = 0; t < 8; ++t) {
    v[t] = fmaxf(acc[t] * d + b2[fl * 8 + t], 0.f);
    lm_ = fmaxf(lm_, v[t]);
  }
#pragma unroll
  for (int off = 32; off > 0; off >>= 1) lm_ = fmaxf(lm_, __shfl_xor(lm_, off));
  float le = 0.f;
#pragma unroll
  for (int t = 0; t < 8; ++t) le += expf(v[t] - lm_);
#pragma unroll
  for (int off = 32; off > 0; off >>= 1) le += __shfl_xor(le, off);
  float logss = logf(le * 0.125f);
  if (grp == 0) {
    float4 o0 = make_float4(v[0] - lm_ - logss, v[1] - lm_ - logss, v[2] - lm_ - logss, v[3] - lm_ - logss);
    float4 o1 = make_float4(v[4] - lm_ - logss, v[5] - lm_ - logss, v[6] - lm_ - logss, v[7] - lm_ - logss);
    *(float4*)&out[(size_t)wid * 64 + fl * 8] = o0;
    *(float4*)&out[(size_t)wid * 64 + fl * 8 + 4] = o1;
  }
}

// ---------------- launch ----------------

extern "C" void kernel_launch(void* const* d_in, const int* in_sizes, int n_in,
                              void* d_out, int out_size, void* d_ws, size_t ws_size,
                              hipStream_t stream) {
  const float* x  = (const float*)d_in[0];
  const int*   ei = (const int*)d_in[1];
  const float* W0 = (const float*)d_in[2];
  const float* b0 = (const float*)d_in[3];
  const float* W1 = (const float*)d_in[4];
  const float* b1 = (const float*)d_in[5];
  const float* W2 = (const float*)d_in[6];
  const float* b2 = (const float*)d_in[7];
  const int* esrc = ei;
  const int* edst = ei + NE;

  char* p = (char*)d_ws;
  auto alloc = [&](size_t bytes) {
    char* q = p;
    p += (bytes + 255) & ~(size_t)255;
    return q;
  };
  float*  dis     = (float*)alloc((size_t)NN * 4);
  int*    row_ptr = (int*)alloc((size_t)(NN + 1) * 4);
  int*    btot    = (int*)alloc(NBK * 4);
  int*    bptr    = (int*)alloc((NBK + 1) * 4);
  int*    csr_src = (int*)alloc((size_t)NE * 4);            // 6.4 MB
  __bf16* tmp     = (__bf16*)alloc((size_t)NN * 128 * 2);   // 25.6 MB
  int*    bucketed  = (int*)tmp;                            // 6.4 MB alias (packed edges)
  int*    bhist     = csr_src;                              // 800 KB alias [bin][block]
  int*    blockbase = csr_src + NBLK * NBK;                 // 800 KB alias [bin][block]

  k1_hist<<<NBLK, 256, 0, stream>>>(edst, bhist);
  kA2<<<(NBK + 3) / 4, 256, 0, stream>>>(bhist, btot);
  kB_bscan<<<1, 1024, 0, stream>>>(btot, bptr);
  kC2<<<(NBK + 3) / 4, 256, 0, stream>>>(bhist, bptr, blockbase);
  k3_scatter<<<NBLK, 256, 0, stream>>>(esrc, edst, blockbase, bucketed);
  k_degfill<<<NBK, 256, 0, stream>>>(bucketed, bptr, row_ptr, dis, csr_src);

  int gblocks = (NN + 127) / 128;
  int ablocks = (NN * 64 + 255) / 256;

  k_gemm<128, 0><<<gblocks, 256, 0, stream>>>(x, W0, nullptr, dis, tmp);
  k_agg128<<<ablocks, 256, 0, stream>>>(tmp, row_ptr, csr_src, dis, (__bf16*)d_out);

  k_gemm<128, 2><<<gblocks, 256, 0, stream>>>(d_out, W1, b0, dis, tmp);
  k_agg128<<<ablocks, 256, 0, stream>>>(tmp, row_ptr, csr_src, dis, (__bf16*)d_out);

  k_gemm<64, 2><<<gblocks, 256, 0, stream>>>(d_out, W2, b1, dis, tmp);
  k_agg64_final<<<ablocks, 256, 0, stream>>>(tmp, row_ptr, csr_src, dis, b2, (float*)d_out);
}

// Round 12
// 423.995 us; speedup vs baseline: 1.0476x; 1.0376x over previous
//
#include <hip/hip_runtime.h>

#define NN 100000
#define NE 1600000
#define NBK 782   // ceil(NN/128) 128-node buckets
#define NBLK 256  // persistent blocks for counting sort
#define CHUNK ((NE + NBLK - 1) / NBLK)  // 6250

typedef __bf16 bf16x2 __attribute__((ext_vector_type(2)));
typedef __bf16 bf16x4 __attribute__((ext_vector_type(4)));
typedef __bf16 bf16x8 __attribute__((ext_vector_type(8)));
typedef float f32x4 __attribute__((ext_vector_type(4)));

// ---------------- W pre-transpose: Wt[n][k] = (bf16)W[k][n], all 3 layers ----------------
// Coalesced reads; writes land in L2 (80 KB total). Lets every GEMM block stage
// its W-LDS with pure b128 copies instead of 64 scalar ds_writes per thread.

__global__ __launch_bounds__(256) void kW_prep(const float* __restrict__ W0, const float* __restrict__ W1,
                                               const float* __restrict__ W2, __bf16* __restrict__ Wt) {
  int i = blockIdx.x * 256 + threadIdx.x;  // 40960 total
  if (i < 16384) {        // W0 128x128, i = k*128+n
    int k = i >> 7, n = i & 127;
    Wt[n * 128 + k] = (__bf16)W0[i];
  } else if (i < 32768) { // W1 128x128
    int j = i - 16384;
    int k = j >> 7, n = j & 127;
    Wt[16384 + n * 128 + k] = (__bf16)W1[j];
  } else if (i < 40960) { // W2 128x64, j = k*64+n
    int j = i - 32768;
    int k = j >> 6, n = j & 63;
    Wt[32768 + n * 128 + k] = (__bf16)W2[j];
  }
}

// ---------------- privatized counting sort by dst-bucket ----------------
// bhist layout: [bin][block]. Edge record packed: (src << 7) | (dst & 127).

__global__ __launch_bounds__(256) void k1_hist(const int* __restrict__ dst, int* __restrict__ bhist) {
  __shared__ int h[NBK];
  int tid = threadIdx.x, b = blockIdx.x;
  for (int i = tid; i < NBK; i += 256) h[i] = 0;
  __syncthreads();
  int base = b * CHUNK, end = min(base + CHUNK, NE);
  for (int e = base + tid; e < end; e += 256) atomicAdd(&h[dst[e] >> 7], 1);
  __syncthreads();
  for (int i = tid; i < NBK; i += 256) bhist[i * NBLK + b] = h[i];
}

__global__ __launch_bounds__(256) void kA2(const int* __restrict__ bhist, int* __restrict__ btot) {
  int w = threadIdx.x >> 6, lane = threadIdx.x & 63;
  int bin = blockIdx.x * 4 + w;
  if (bin >= NBK) return;
  int4 v = *(const int4*)(bhist + bin * NBLK + lane * 4);
  int s = v.x + v.y + v.z + v.w;
#pragma unroll
  for (int off = 32; off > 0; off >>= 1) s += __shfl_xor(s, off);
  if (lane == 0) btot[bin] = s;
}

__global__ __launch_bounds__(1024) void kB_bscan(const int* __restrict__ btot, int* __restrict__ bptr) {
  __shared__ int s[1024];
  int tid = threadIdx.x;
  int v = (tid < NBK) ? btot[tid] : 0;
  s[tid] = v;
  __syncthreads();
  for (int off = 1; off < 1024; off <<= 1) {
    int t = (tid >= off) ? s[tid - off] : 0;
    __syncthreads();
    s[tid] += t;
    __syncthreads();
  }
  if (tid < NBK) bptr[tid + 1] = s[tid];
  if (tid == 0) bptr[0] = 0;
}

__global__ __launch_bounds__(256) void kC2(const int* __restrict__ bhist, const int* __restrict__ bptr,
                                           int* __restrict__ blockbase) {
  int w = threadIdx.x >> 6, lane = threadIdx.x & 63;
  int bin = blockIdx.x * 4 + w;
  if (bin >= NBK) return;
  int4 v = *(const int4*)(bhist + bin * NBLK + lane * 4);
  int ls = v.x + v.y + v.z + v.w;
  int incl = ls;
#pragma unroll
  for (int off = 1; off < 64; off <<= 1) {
    int t = __shfl_up(incl, off);
    if (lane >= off) incl += t;
  }
  int base = bptr[bin] + incl - ls;
  int4 o;
  o.x = base;
  o.y = base + v.x;
  o.z = base + v.x + v.y;
  o.w = base + v.x + v.y + v.z;
  *(int4*)(blockbase + bin * NBLK + lane * 4) = o;
}

__global__ __launch_bounds__(256) void k3_scatter(const int* __restrict__ src, const int* __restrict__ dst,
                                                  const int* __restrict__ blockbase, int* __restrict__ bucketed) {
  __shared__ int cur[NBK];
  int tid = threadIdx.x, b = blockIdx.x;
  for (int i = tid; i < NBK; i += 256) cur[i] = blockbase[i * NBLK + b];
  __syncthreads();
  int base = b * CHUNK, end = min(base + CHUNK, NE);
  for (int e = base + tid; e < end; e += 256) {
    int d = dst[e];
    int pos = atomicAdd(&cur[d >> 7], 1);
    bucketed[pos] = (src[e] << 7) | (d & 127);
  }
}

__global__ __launch_bounds__(256) void k_degfill(const int* __restrict__ bucketed, const int* __restrict__ bptr,
                                                 int* __restrict__ row_ptr, float* __restrict__ dis,
                                                 int* __restrict__ csr_src) {
  __shared__ int deg[128];
  __shared__ int sc[128];
  __shared__ int cur[128];
  int b = blockIdx.x, tid = threadIdx.x;
  int nb0 = b << 7;
  if (tid < 128) deg[tid] = 0;
  __syncthreads();
  int beg = bptr[b], end = bptr[b + 1];
  for (int e = beg + tid; e < end; e += 256) atomicAdd(&deg[bucketed[e] & 127], 1);
  __syncthreads();
  if (tid < 128) sc[tid] = deg[tid];
  __syncthreads();
  for (int off = 1; off < 128; off <<= 1) {
    int t = (tid >= off && tid < 128) ? sc[tid - off] : 0;
    __syncthreads();
    if (tid < 128) sc[tid] += t;
    __syncthreads();
  }
  if (tid < 128) {
    cur[tid] = beg + sc[tid] - deg[tid];
    if (nb0 + tid < NN) {
      row_ptr[nb0 + tid + 1] = beg + sc[tid];
      dis[nb0 + tid] = rsqrtf((float)(deg[tid] + 1));
      if (b == 0 && tid == 0) row_ptr[0] = 0;
    }
  }
  __syncthreads();
  for (int e = beg + tid; e < end; e += 256) {
    int pk = bucketed[e];
    int pos = atomicAdd(&cur[pk & 127], 1);
    csr_src[pos] = pk >> 7;
  }
}

// ---------------- bf16 MFMA GEMM, direct-A-load variant ----------------
// A fragments load straight from global (layout A[m=lane&15][k=(lane>>4)*8+j]
// maps to row-major 16 B/lane reads) — no lA staging, ONE barrier total.
// Wt is pre-transposed bf16 [n][k]; staged to LDS via b128 copies.
// MODE 0: A fp32 (x). MODE 2: A bf16 (agg in d_out) with relu(a+bias[k]).

template <int BN, int MODE>
__global__ __launch_bounds__(256) void k_gemm(const void* __restrict__ Av, const __bf16* __restrict__ Wt,
                                              const float* __restrict__ bias, const float* __restrict__ dis,
                                              __bf16* __restrict__ out) {
  constexpr int LDK = 136;  // 128 + 8 pad: row stride 272 B -> 4-bank rotation
  constexpr int NT = BN / 32;
  __shared__ __bf16 lB[BN * LDK];

  const int tid = threadIdx.x;
  const int rowBase = blockIdx.x * 128;
  const int lane = tid & 63;
  const int wid = tid >> 6;
  const int wm = (wid & 1) * 64;
  const int wn = (wid >> 1) * (BN / 2);
  const int lm = lane & 15;
  const int kg = lane >> 4;

  // stage whole W (BN x 128) into LDS: pure b128 copies
  for (int c = tid; c < 16 * BN; c += 256) {
    int n = c >> 4;
    int koff = (c & 15) * 8;
    bf16x8 w = *(const bf16x8*)(Wt + n * 128 + koff);
    *(bf16x8*)&lB[n * LDK + koff] = w;
  }
  __syncthreads();

  f32x4 acc[4][NT] = {};
  const bool full = (rowBase + 128 <= NN);

#pragma unroll 2
  for (int ks = 0; ks < 128; ks += 32) {
    int k0 = ks + kg * 8;
    bf16x8 af[4];
    if constexpr (MODE == 0) {
      const float* A = (const float*)Av;
#pragma unroll
      for (int tm = 0; tm < 4; ++tm) {
        int gr = rowBase + wm + tm * 16 + lm;
        f32x4 a0 = {}, a1 = {};
        if (full || gr < NN) {
          a0 = *(const f32x4*)(A + (size_t)gr * 128 + k0);
          a1 = *(const f32x4*)(A + (size_t)gr * 128 + k0 + 4);
        }
        af[tm] = bf16x8{(__bf16)a0[0], (__bf16)a0[1], (__bf16)a0[2], (__bf16)a0[3],
                        (__bf16)a1[0], (__bf16)a1[1], (__bf16)a1[2], (__bf16)a1[3]};
      }
    } else {
      const __bf16* A = (const __bf16*)Av;
      f32x4 b0 = *(const f32x4*)(bias + k0);
      f32x4 b1 = *(const f32x4*)(bias + k0 + 4);
#pragma unroll
      for (int tm = 0; tm < 4; ++tm) {
        int gr = rowBase + wm + tm * 16 + lm;
        bf16x8 v = {};
        if (full || gr < NN) v = *(const bf16x8*)(A + (size_t)gr * 128 + k0);
        af[tm] = bf16x8{(__bf16)fmaxf((float)v[0] + b0[0], 0.f), (__bf16)fmaxf((float)v[1] + b0[1], 0.f),
                        (__bf16)fmaxf((float)v[2] + b0[2], 0.f), (__bf16)fmaxf((float)v[3] + b0[3], 0.f),
                        (__bf16)fmaxf((float)v[4] + b1[0], 0.f), (__bf16)fmaxf((float)v[5] + b1[1], 0.f),
                        (__bf16)fmaxf((float)v[6] + b1[2], 0.f), (__bf16)fmaxf((float)v[7] + b1[3], 0.f)};
      }
    }
    bf16x8 bfr[NT];
#pragma unroll
    for (int tn = 0; tn < NT; ++tn)
      bfr[tn] = *(const bf16x8*)&lB[(wn + tn * 16 + lm) * LDK + k0];
#pragma unroll
    for (int tm = 0; tm < 4; ++tm)
#pragma unroll
      for (int tn = 0; tn < NT; ++tn)
        acc[tm][tn] = __builtin_amdgcn_mfma_f32_16x16x32_bf16(af[tm], bfr[tn], acc[tm][tn], 0, 0, 0);
  }

  // epilogue: C/D layout col=lane&15, row=(lane>>4)*4+reg; scale by dis[row]
#pragma unroll
  for (int tm = 0; tm < 4; ++tm) {
    int r0 = rowBase + wm + tm * 16 + kg * 4;
#pragma unroll
    for (int tn = 0; tn < NT; ++tn) {
      int c0 = wn + tn * 16 + lm;
#pragma unroll
      for (int r = 0; r < 4; ++r) {
        int gr = r0 + r;
        if (full || gr < NN) out[(size_t)gr * BN + c0] = (__bf16)(acc[tm][tn][r] * dis[gr]);
      }
    }
  }
}

// ---------------- grouped pull aggregation (F=128): at LLC compulsory floor ----------------

__global__ __launch_bounds__(256) void k_agg128(const __bf16* __restrict__ tmp, const int* __restrict__ row_ptr,
                                                const int* __restrict__ csr_src, const float* __restrict__ dis,
                                                __bf16* __restrict__ agg) {
  int wid = (blockIdx.x * 256 + threadIdx.x) >> 6;
  int lane = threadIdx.x & 63;
  if (wid >= NN) return;
  int grp = lane >> 4;   // 0..3
  int fl = lane & 15;    // features [fl*8, fl*8+8)

  float acc[8];
  if (grp == 0) {
    bf16x8 sv = *(const bf16x8*)&tmp[(size_t)wid * 128 + fl * 8];
#pragma unroll
    for (int t = 0; t < 8; ++t) acc[t] = (float)sv[t];
  } else {
#pragma unroll
    for (int t = 0; t < 8; ++t) acc[t] = 0.f;
  }

  int beg = row_ptr[wid];
  int end = row_ptr[wid + 1];
  for (int base = beg; base < end; base += 64) {
    int cnt = min(64, end - base);
    int sidx = (base + lane < end) ? csr_src[base + lane] : 0;
    int i = 0;
    for (; i + 16 <= cnt; i += 16) {
      bf16x8 v[4];
#pragma unroll
      for (int u = 0; u < 4; ++u) {
        int s = __shfl(sidx, i + u * 4 + grp);
        v[u] = *(const bf16x8*)&tmp[(size_t)s * 128 + fl * 8];
      }
#pragma unroll
      for (int u = 0; u < 4; ++u)
#pragma unroll
        for (int t = 0; t < 8; ++t) acc[t] += (float)v[u][t];
    }
    for (; i + 4 <= cnt; i += 4) {
      int s = __shfl(sidx, i + grp);
      bf16x8 v = *(const bf16x8*)&tmp[(size_t)s * 128 + fl * 8];
#pragma unroll
      for (int t = 0; t < 8; ++t) acc[t] += (float)v[t];
    }
    if (i < cnt) {
      int idx = i + grp;
      int s = __shfl(sidx, idx & 63);
      if (idx < cnt) {
        bf16x8 v = *(const bf16x8*)&tmp[(size_t)s * 128 + fl * 8];
#pragma unroll
        for (int t = 0; t < 8; ++t) acc[t] += (float)v[t];
      }
    }
  }

#pragma unroll
  for (int t = 0; t < 8; ++t) acc[t] += __shfl_xor(acc[t], 16);
#pragma unroll
  for (int t = 0; t < 8; ++t) acc[t] += __shfl_xor(acc[t], 32);

  if (grp == 0) {
    float d = dis[wid];
    bf16x8 o;
#pragma unroll
    for (int t = 0; t < 8; ++t) o[t] = (__bf16)(acc[t] * d);
    *(bf16x8*)&agg[(size_t)wid * 128 + fl * 8] = o;
  }
}

// ---------------- F=64 grouped aggregation fused with bias+relu+log_softmax ----------------

__global__ __launch_bounds__(256) void k_agg64_final(const __bf16* __restrict__ tmp, const int* __restrict__ row_ptr,
                                                     const int* __restrict__ csr_src, const float* __restrict__ dis,
                                                     const float* __restrict__ b2, float* __restrict__ out) {
  int wid = (blockIdx.x * 256 + threadIdx.x) >> 6;
  int lane = threadIdx.x & 63;
  if (wid >= NN) return;
  int grp = lane >> 3;  // 0..7
  int fl = lane & 7;    // features [fl*8, fl*8+8)

  float acc[8];
  if (grp == 0) {
    bf16x8 sv = *(const bf16x8*)&tmp[(size_t)wid * 64 + fl * 8];
#pragma unroll
    for (int t = 0; t < 8; ++t) acc[t] = (float)sv[t];
  } else {
#pragma unroll
    for (int t = 0; t < 8; ++t) acc[t] = 0.f;
  }

  int beg = row_ptr[wid];
  int end = row_ptr[wid + 1];
  for (int base = beg; base < end; base += 64) {
    int cnt = min(64, end - base);
    int sidx = (base + lane < end) ? csr_src[base + lane] : 0;
    int i = 0;
    for (; i + 16 <= cnt; i += 16) {
      int s0 = __shfl(sidx, i + grp);
      int s1 = __shfl(sidx, i + 8 + grp);
      bf16x8 v0 = *(const bf16x8*)&tmp[(size_t)s0 * 64 + fl * 8];
      bf16x8 v1 = *(const bf16x8*)&tmp[(size_t)s1 * 64 + fl * 8];
#pragma unroll
      for (int t = 0; t < 8; ++t) acc[t] += (float)v0[t] + (float)v1[t];
    }
    for (; i + 8 <= cnt; i += 8) {
      int s = __shfl(sidx, i + grp);
      bf16x8 v = *(const bf16x8*)&tmp[(size_t)s * 64 + fl * 8];
#pragma unroll
      for (int t = 0; t < 8; ++t) acc[t] += (float)v[t];
    }
    if (i < cnt) {
      int idx = i + grp;
      int s = __shfl(sidx, idx & 63);
      if (idx < cnt) {
        bf16x8 v = *(const bf16x8*)&tmp[(size_t)s * 64 + fl * 8];
#pragma unroll
        for (int t = 0; t < 8; ++t) acc[t] += (float)v[t];
      }
    }
  }

#pragma unroll
  for (int t = 0; t < 8; ++t) acc[t] += __shfl_xor(acc[t], 8);
#pragma unroll
  for (int t = 0; t < 8; ++t) acc[t] += __shfl_xor(acc[t], 16);
#pragma unroll
  for (int t = 0; t < 8; ++t) acc[t] += __shfl_xor(acc[t], 32);

  float d = dis[wid];
  float v[8], lm_ = -1e30f;
#pragma unroll
  for (int t = 0; t < 8; ++t) {
    v[t] = fmaxf(acc[t] * d + b2[fl * 8 + t], 0.f);
    lm_ = fmaxf(lm_, v[t]);
  }
#pragma unroll
  for (int off = 32; off > 0; off >>= 1) lm_ = fmaxf(lm_, __shfl_xor(lm_, off));
  float le = 0.f;
#pragma unroll
  for (int t = 0; t < 8; ++t) le += expf(v[t] - lm_);
#pragma unroll
  for (int off = 32; off > 0; off >>= 1) le += __shfl_xor(le, off);
  float logss = logf(le * 0.125f);
  if (grp == 0) {
    float4 o0 = make_float4(v[0] - lm_ - logss, v[1] - lm_ - logss, v[2] - lm_ - logss, v[3] - lm_ - logss);
    float4 o1 = make_float4(v[4] - lm_ - logss, v[5] - lm_ - logss, v[6] - lm_ - logss, v[7] - lm_ - logss);
    *(float4*)&out[(size_t)wid * 64 + fl * 8] = o0;
    *(float4*)&out[(size_t)wid * 64 + fl * 8 + 4] = o1;
  }
}

// ---------------- launch ----------------

extern "C" void kernel_launch(void* const* d_in, const int* in_sizes, int n_in,
                              void* d_out, int out_size, void* d_ws, size_t ws_size,
                              hipStream_t stream) {
  const float* x  = (const float*)d_in[0];
  const int*   ei = (const int*)d_in[1];
  const float* W0 = (const float*)d_in[2];
  const float* b0 = (const float*)d_in[3];
  const float* W1 = (const float*)d_in[4];
  const float* b1 = (const float*)d_in[5];
  const float* W2 = (const float*)d_in[6];
  const float* b2 = (const float*)d_in[7];
  const int* esrc = ei;
  const int* edst = ei + NE;

  char* p = (char*)d_ws;
  auto alloc = [&](size_t bytes) {
    char* q = p;
    p += (bytes + 255) & ~(size_t)255;
    return q;
  };
  float*  dis     = (float*)alloc((size_t)NN * 4);
  int*    row_ptr = (int*)alloc((size_t)(NN + 1) * 4);
  int*    btot    = (int*)alloc(NBK * 4);
  int*    bptr    = (int*)alloc((NBK + 1) * 4);
  __bf16* Wt      = (__bf16*)alloc(40960 * 2);              // 80 KB: Wt0|Wt1|Wt2
  int*    csr_src = (int*)alloc((size_t)NE * 4);            // 6.4 MB
  __bf16* tmp     = (__bf16*)alloc((size_t)NN * 128 * 2);   // 25.6 MB
  int*    bucketed  = (int*)tmp;                            // 6.4 MB alias (packed edges)
  int*    bhist     = csr_src;                              // 800 KB alias [bin][block]
  int*    blockbase = csr_src + NBLK * NBK;                 // 800 KB alias [bin][block]

  kW_prep<<<160, 256, 0, stream>>>(W0, W1, W2, Wt);
  k1_hist<<<NBLK, 256, 0, stream>>>(edst, bhist);
  kA2<<<(NBK + 3) / 4, 256, 0, stream>>>(bhist, btot);
  kB_bscan<<<1, 1024, 0, stream>>>(btot, bptr);
  kC2<<<(NBK + 3) / 4, 256, 0, stream>>>(bhist, bptr, blockbase);
  k3_scatter<<<NBLK, 256, 0, stream>>>(esrc, edst, blockbase, bucketed);
  k_degfill<<<NBK, 256, 0, stream>>>(bucketed, bptr, row_ptr, dis, csr_src);

  int gblocks = (NN + 127) / 128;  // 782
  int ablocks = (NN * 64 + 255) / 256;

  k_gemm<128, 0><<<gblocks, 256, 0, stream>>>(x, Wt, nullptr, dis, tmp);
  k_agg128<<<ablocks, 256, 0, stream>>>(tmp, row_ptr, csr_src, dis, (__bf16*)d_out);

  k_gemm<128, 2><<<gblocks, 256, 0, stream>>>(d_out, Wt + 16384, b0, dis, tmp);
  k_agg128<<<ablocks, 256, 0, stream>>>(tmp, row_ptr, csr_src, dis, (__bf16*)d_out);

  k_gemm<64, 2><<<gblocks, 256, 0, stream>>>(d_out, Wt + 32768, b1, dis, tmp);
  k_agg64_final<<<ablocks, 256, 0, stream>>>(tmp, row_ptr, csr_src, dis, b2, (float*)d_out);
}